// Round 2
// baseline (1546.505 us; speedup 1.0000x reference)
//
#include <hip/hip_runtime.h>
#include <math.h>

// DualTokenQFormer — algebraic reduction: single-query cross-attention means
// K/V projections (the 344 GF bulk of the reference) collapse to
//   logits = frame @ (Wk_h @ q_h)   and   O_h = (sum_j att_hj * frame_j) @ Wv_h
// so the whole op becomes a few streaming passes over frame_tokens (134 MB, L3-resident).

static constexpr int NT  = 32768;
static constexpr int DIM = 1024;
static constexpr int NL  = 2;

// workspace layout (float offsets)
static constexpr size_t W_SCORE=0, W_HIST1=32768, W_HIST2=98304, W_META=163840,
 W_EQIDX=163904, W_SALIDX=168000, W_STATS=180224, W_Q=1228800, W_QLN1=1230848,
 W_QLN2=1232896, W_QLN3=1234944, W_QKV=1236992, W_OSELF=1243136,
 W_QP_G=1245184, W_QP_S=1246208, W_ES_G=1247232, W_ES_S=1247296,
 W_O_G=1247360, W_O_S=1248384, W_QPROJ_G=1249408, W_QPROJ_S=1265792,
 W_CTX_G=1282176, W_CTX_S=1298560, W_FFNH=1314944,
 W_SCORES_G=1323136, W_SCORES_S=1847424, W_PART_G=1978496, W_PART_S=6172800;
// total ≈ 7.22M floats ≈ 29 MB

__device__ __forceinline__ float wred(float v){
#pragma unroll
  for (int off=1; off<64; off<<=1) v += __shfl_xor(v, off, 64);
  return v;
}
__device__ __forceinline__ float gelu_f(float x){
  return 0.5f*x*(1.0f + erff(x*0.70710678118654752440f));
}

// ---- phase 0: per-row norm (saliency score), per-dim sum & max, zero hists ----
__global__ __launch_bounds__(256) void k_stats(const float* __restrict__ fr, float* __restrict__ ws){
  int b = blockIdx.x, tid = threadIdx.x, wv = tid>>6, l = tid&63;
  ((unsigned*)ws)[W_HIST1 + (size_t)b*256 + tid] = 0u;     // 512*256 = 131072 covers hist1+hist2
  if (b==0 && tid<64) ((unsigned*)ws)[W_META + tid] = 0u;
  float ssum[16], smx[16];
#pragma unroll
  for (int i=0;i<16;i++){ ssum[i]=0.f; smx[i]=-3.402823466e38f; }
  int row0 = b*64 + wv*16;
  for (int r=0;r<16;r++){
    const float* rp = fr + (size_t)(row0+r)*DIM;
    float nrm = 0.f;
#pragma unroll
    for (int p=0;p<4;p++){
      float4 v = *(const float4*)(rp + p*256 + l*4);
      ssum[p*4+0]+=v.x; ssum[p*4+1]+=v.y; ssum[p*4+2]+=v.z; ssum[p*4+3]+=v.w;
      smx[p*4+0]=fmaxf(smx[p*4+0],v.x); smx[p*4+1]=fmaxf(smx[p*4+1],v.y);
      smx[p*4+2]=fmaxf(smx[p*4+2],v.z); smx[p*4+3]=fmaxf(smx[p*4+3],v.w);
      nrm += v.x*v.x + v.y*v.y + v.z*v.z + v.w*v.w;
    }
    nrm = wred(nrm);
    if (l==0) ws[W_SCORE + row0 + r] = sqrtf(nrm);
  }
  __shared__ float lsum[1024], lmax[1024];
  for (int w=0; w<4; w++){
    if (wv==w){
#pragma unroll
      for (int p=0;p<4;p++)
#pragma unroll
        for (int i=0;i<4;i++){
          int d = p*256 + l*4 + i;
          if (w==0){ lsum[d]=ssum[p*4+i]; lmax[d]=smx[p*4+i]; }
          else     { lsum[d]+=ssum[p*4+i]; lmax[d]=fmaxf(lmax[d],smx[p*4+i]); }
        }
    }
    __syncthreads();
  }
  float* st = ws + W_STATS + (size_t)b*2048;
  for (int i=tid;i<1024;i+=256){ st[i]=lsum[i]; st[1024+i]=lmax[i]; }
}

// ---- reduce stats -> q init (mean tok / max tok + learned embeds) ----
__global__ __launch_bounds__(256) void k_reduce(float* __restrict__ ws,
    const float* __restrict__ qb, const float* __restrict__ re, const float* __restrict__ te){
  int d = blockIdx.x*256 + threadIdx.x;
  const float* st = ws + W_STATS;
  float s=0.f, m=-3.402823466e38f;
  for (int c=0;c<512;c++){ s += st[(size_t)c*2048 + d]; m = fmaxf(m, st[(size_t)c*2048 + 1024 + d]); }
  float mean = s * (1.0f/32768.0f);
  ws[W_Q + d]        = mean + qb[d]        + re[d]        + te[d];
  ws[W_Q + 1024 + d] = m    + qb[1024 + d] + re[1024 + d] + te[d];
}

// ---- radix-select top-8192 on f32 score bits (non-negative => uint-monotonic) ----
__global__ void k_hist1(float* ws){
  int i = blockIdx.x*256 + threadIdx.x;
  unsigned u = __float_as_uint(ws[W_SCORE + i]);
  atomicAdd(((unsigned*)ws) + W_HIST1 + (u>>16), 1u);
}
__global__ void k_hist2(float* ws){
  unsigned* meta = (unsigned*)ws + W_META;
  int i = blockIdx.x*256 + threadIdx.x;
  unsigned u = __float_as_uint(ws[W_SCORE + i]);
  if ((u>>16) == meta[0]) atomicAdd(((unsigned*)ws) + W_HIST2 + (u & 0xFFFFu), 1u);
}
__global__ __launch_bounds__(1024) void k_find(float* ws, int which){
  unsigned* hist = (unsigned*)ws + (which ? W_HIST2 : W_HIST1);
  unsigned* meta = (unsigned*)ws + W_META;
  __shared__ unsigned ls[1024];
  int t = threadIdx.x;
  unsigned kk = which ? (8192u - meta[1]) : 8192u;
  unsigned s = 0;
  for (int i=0;i<64;i++) s += hist[t*64 + i];
  ls[t] = s; __syncthreads();
  for (int off=1; off<1024; off<<=1){
    unsigned v = ls[t] + ((t+off<1024)? ls[t+off] : 0u);
    __syncthreads(); ls[t] = v; __syncthreads();
  }
  unsigned suf_in = ls[t];
  unsigned suf_ex = (t<1023) ? ls[t+1] : 0u;
  if (suf_in >= kk && suf_ex < kk){
    unsigned run = suf_ex;
    for (int i=63;i>=0;i--){
      unsigned c = hist[t*64+i];
      if (run + c >= kk){
        if (!which){ meta[0] = (unsigned)(t*64+i); meta[1] = run; }
        else { meta[2] = (meta[0]<<16) | (unsigned)(t*64+i); meta[3] = kk - run; }
        break;
      }
      run += c;
    }
  }
}
__global__ void k_mark(float* ws){
  unsigned* meta = (unsigned*)ws + W_META;
  unsigned* sal  = (unsigned*)ws + W_SALIDX;
  unsigned* eq   = (unsigned*)ws + W_EQIDX;
  int i = blockIdx.x*256 + threadIdx.x;
  unsigned u = __float_as_uint(ws[W_SCORE + i]);
  unsigned U = meta[2];
  if (u > U){ unsigned p = atomicAdd(&meta[5], 1u); sal[p] = (unsigned)i; }
  else if (u == U){ unsigned p = atomicAdd(&meta[4], 1u); if (p < 4096u) eq[p] = (unsigned)i; }
}
__global__ __launch_bounds__(256) void k_eqsel(float* ws){
  unsigned* meta = (unsigned*)ws + W_META;
  unsigned* sal  = (unsigned*)ws + W_SALIDX;
  unsigned* eq   = (unsigned*)ws + W_EQIDX;
  unsigned n = meta[4]; if (n > 4096u) n = 4096u;
  unsigned r = meta[3];
  for (unsigned e = threadIdx.x; e < n; e += 256){
    unsigned me = eq[e];
    unsigned rank = 0;
    for (unsigned j=0;j<n;j++) rank += (eq[j] < me) ? 1u : 0u;
    if (rank < r){ unsigned p = atomicAdd(&meta[5], 1u); sal[p] = me; }
  }
}

// ---- LayerNorm over rows of length 1024 (+ optional zero of a scratch range) ----
__global__ __launch_bounds__(256) void k_ln(const float* __restrict__ in,
    const float* __restrict__ g, const float* __restrict__ bt, float* __restrict__ out,
    int n_rows, float* zptr, int zlen){
  int b = blockIdx.x, tid = threadIdx.x, wv = tid>>6;
  if (b >= n_rows){
    int zb = b - n_rows;
    int i0 = zb*1024 + tid;
#pragma unroll
    for (int k=0;k<4;k++){ int i = i0 + k*256; if (i < zlen) zptr[i] = 0.f; }
    return;
  }
  const float* x = in + (size_t)b*1024;
  float4 v = *(const float4*)(x + tid*4);
  float s  = v.x+v.y+v.z+v.w;
  float s2 = v.x*v.x+v.y*v.y+v.z*v.z+v.w*v.w;
  s = wred(s); s2 = wred(s2);
  __shared__ float rs[4], rq[4];
  if ((tid&63)==0){ rs[wv]=s; rq[wv]=s2; }
  __syncthreads();
  s = rs[0]+rs[1]+rs[2]+rs[3]; s2 = rq[0]+rq[1]+rq[2]+rq[3];
  float m = s * (1.0f/1024.0f);
  float var = s2 * (1.0f/1024.0f) - m*m;
  float rstd = rsqrtf(var + 1e-5f);
  float4 gv = *(const float4*)(g + tid*4);
  float4 bv = *(const float4*)(bt + tid*4);
  float4 o;
  o.x = (v.x-m)*rstd*gv.x + bv.x; o.y = (v.y-m)*rstd*gv.y + bv.y;
  o.z = (v.z-m)*rstd*gv.z + bv.z; o.w = (v.w-m)*rstd*gv.w + bv.w;
  *(float4*)(out + (size_t)b*1024 + tid*4) = o;
}

// ---- generic K-chunked GEMV with f32 atomic partials; bias folded into chunk 0;
//      optional GELU applied to the input row during LDS preload (for FFN2) ----
__global__ __launch_bounds__(256) void k_gemv(const float* __restrict__ in, int in_stride,
    const float* __restrict__ W, int ldw, const float* __restrict__ bias,
    float* __restrict__ out, int out_stride, int K, int n_out, int kchunk, int gelu_in){
  extern __shared__ float sin_[];
  int tid = threadIdx.x;
  const float* inr = in + (size_t)blockIdx.y * in_stride;
  for (int i = tid*4; i < K; i += 1024){
    float4 v = *(const float4*)(inr + i);
    if (gelu_in){ v.x=gelu_f(v.x); v.y=gelu_f(v.y); v.z=gelu_f(v.z); v.w=gelu_f(v.w); }
    *(float4*)(sin_ + i) = v;
  }
  __syncthreads();
  int wid = blockIdx.x*4 + (tid>>6);
  int l = tid & 63;
  int n_os = n_out >> 8;
  int os  = (wid % n_os) * 256;
  int kch = wid / n_os;
  int f0 = kch * kchunk;
  int o = os + l*4;
  float a0=0,a1=0,a2=0,a3=0;
  if (kch==0 && bias){ a0=bias[o]; a1=bias[o+1]; a2=bias[o+2]; a3=bias[o+3]; }
  const float* Wp = W + (size_t)f0*ldw + o;
#pragma unroll 4
  for (int f=0; f<kchunk; f++){
    float sv = sin_[f0+f];
    float4 w4 = *(const float4*)(Wp + (size_t)f*ldw);
    a0 += sv*w4.x; a1 += sv*w4.y; a2 += sv*w4.z; a3 += sv*w4.w;
  }
  float* op = out + (size_t)blockIdx.y*out_stride + o;
  atomicAdd(op+0,a0); atomicAdd(op+1,a1); atomicAdd(op+2,a2); atomicAdd(op+3,a3);
}

// ---- 2-token self-attention core (qkv -> o), 16 heads ----
__global__ __launch_bounds__(256) void k_attn_self(float* __restrict__ ws){
  const float* qkv = ws + W_QKV;
  float* o = ws + W_OSELF;
  int tid = threadIdx.x, wv = tid>>6, l = tid&63;
#pragma unroll
  for (int p=0;p<4;p++){
    int off = (wv + p*4)*64 + l;
    float qa = qkv[off],        qb = qkv[3072+off];
    float ka = qkv[1024+off],   kb = qkv[3072+1024+off];
    float va = qkv[2048+off],   vb = qkv[3072+2048+off];
    float s00 = wred(qa*ka)*0.125f, s01 = wred(qa*kb)*0.125f;
    float s10 = wred(qb*ka)*0.125f, s11 = wred(qb*kb)*0.125f;
    float m0 = fmaxf(s00,s01); float e00=expf(s00-m0), e01=expf(s01-m0); float r0=1.f/(e00+e01);
    float m1 = fmaxf(s10,s11); float e10=expf(s10-m1), e11=expf(s11-m1); float r1=1.f/(e10+e11);
    o[off]        = (e00*va + e01*vb)*r0;
    o[1024 + off] = (e10*va + e11*vb)*r1;
  }
}

// ---- qprojk[h][d] = (Wk[d, h-slice] . qp[h-slice]) / 8 for both branches ----
__global__ __launch_bounds__(256) void k_qproj(const float* __restrict__ cgw,
    const float* __restrict__ csw, float* __restrict__ ws){
  int br = blockIdx.x >> 4, h = blockIdx.x & 15, tid = threadIdx.x;
  const float* W  = br ? csw : cgw;
  const float* qp = ws + (br ? W_QP_S : W_QP_G);
  float* qpr      = ws + (br ? W_QPROJ_S : W_QPROJ_G);
  __shared__ float qs[64];
  if (tid < 64) qs[tid] = qp[h*64 + tid];
  __syncthreads();
#pragma unroll
  for (int dd=0; dd<4; dd++){
    int d = tid*4 + dd;
    const float* wr = W + (size_t)d*3072 + 1024 + h*64;
    float acc = 0.f;
#pragma unroll
    for (int c4=0;c4<16;c4++){
      float4 w4 = *(const float4*)(wr + c4*4);
      acc += w4.x*qs[c4*4] + w4.y*qs[c4*4+1] + w4.z*qs[c4*4+2] + w4.w*qs[c4*4+3];
    }
    qpr[h*1024 + d] = acc * 0.125f;
  }
}

// ---- big pass 1: logits for all tokens (global: blocks 0..511, salient: 512..639)
//      qproj held in registers, 4 heads per wave; also accumulates sum(exp) ----
__global__ __launch_bounds__(256) void k_scores(const float* __restrict__ fr, float* __restrict__ ws){
  int b = blockIdx.x, tid = threadIdx.x, wv = tid>>6, l = tid&63;
  int br = (b >= 512) ? 1 : 0;
  int bb = br ? b - 512 : b;
  __shared__ unsigned idx[64];
  if (br && tid < 64) idx[tid] = ((unsigned*)ws)[W_SALIDX + bb*64 + tid];
  __syncthreads();
  const float* qpr = ws + (br ? W_QPROJ_S : W_QPROJ_G);
  float* sc = ws + (br ? W_SCORES_S : W_SCORES_G);
  float* es = ws + (br ? W_ES_S : W_ES_G);
  int hb = wv*4;
  float4 qv[4][4];
#pragma unroll
  for (int h=0;h<4;h++)
#pragma unroll
    for (int p=0;p<4;p++)
      qv[h][p] = *(const float4*)(qpr + (size_t)(hb+h)*1024 + p*256 + l*4);
  float es0=0,es1=0,es2=0,es3=0;
  for (int rr=0; rr<64; rr++){
    int jj = bb*64 + rr;
    int j  = br ? (int)idx[rr] : jj;
    const float* rp = fr + (size_t)j*DIM;
    float4 f0 = *(const float4*)(rp +        l*4);
    float4 f1 = *(const float4*)(rp + 256 +  l*4);
    float4 f2 = *(const float4*)(rp + 512 +  l*4);
    float4 f3 = *(const float4*)(rp + 768 +  l*4);
    float s[4];
#pragma unroll
    for (int h=0;h<4;h++){
      s[h] = f0.x*qv[h][0].x + f0.y*qv[h][0].y + f0.z*qv[h][0].z + f0.w*qv[h][0].w
           + f1.x*qv[h][1].x + f1.y*qv[h][1].y + f1.z*qv[h][1].z + f1.w*qv[h][1].w
           + f2.x*qv[h][2].x + f2.y*qv[h][2].y + f2.z*qv[h][2].z + f2.w*qv[h][2].w
           + f3.x*qv[h][3].x + f3.y*qv[h][3].y + f3.z*qv[h][3].z + f3.w*qv[h][3].w;
      s[h] = wred(s[h]);
    }
    if (l==0) *(float4*)(sc + (size_t)jj*16 + hb) = make_float4(s[0],s[1],s[2],s[3]);
    es0 += expf(s[0]); es1 += expf(s[1]); es2 += expf(s[2]); es3 += expf(s[3]);
  }
  if (l==0){
    atomicAdd(es+hb+0, es0); atomicAdd(es+hb+1, es1);
    atomicAdd(es+hb+2, es2); atomicAdd(es+hb+3, es3);
  }
}

// ---- big pass 2: ctx[h][d] = sum_j att[h,j]*frame[j][d]; weights normalized in LDS preload;
//      per-chunk partials to ws (reduced by k_ctxred) ----
__global__ __launch_bounds__(256) void k_ctx(const float* __restrict__ fr, float* __restrict__ ws){
  int b = blockIdx.x, tid = threadIdx.x, wv = tid>>6, l = tid&63;
  int br = (b >= 256) ? 1 : 0;
  int chunk = br ? b - 256 : b;
  const float* sc = ws + (br ? W_SCORES_S : W_SCORES_G);
  const float* es = ws + (br ? W_ES_S : W_ES_G);
  float* part = ws + (br ? W_PART_S : W_PART_G);
  __shared__ float wl[128*16];
  __shared__ float inv[16];
  __shared__ unsigned idx[128];
  int rowbase = chunk*128;
  if (tid < 16) inv[tid] = 1.0f/es[tid];
  if (br && tid < 128) idx[tid] = ((unsigned*)ws)[W_SALIDX + rowbase + tid];
  __syncthreads();
  {
    int i0 = tid*8;
#pragma unroll
    for (int k2=0;k2<8;k2++){
      int e = i0 + k2;
      wl[e] = expf(sc[(size_t)rowbase*16 + e]) * inv[e & 15];
    }
  }
  __syncthreads();
  int d = wv*256 + l*4;
  float4 acc[16];
#pragma unroll
  for (int h=0;h<16;h++) acc[h] = make_float4(0.f,0.f,0.f,0.f);
  for (int r=0;r<128;r++){
    int j = br ? (int)idx[r] : rowbase + r;
    float4 f4 = *(const float4*)(fr + (size_t)j*DIM + d);
#pragma unroll
    for (int h4=0;h4<4;h4++){
      float4 w4 = *(const float4*)(wl + r*16 + h4*4);
      acc[h4*4+0].x += f4.x*w4.x; acc[h4*4+0].y += f4.y*w4.x; acc[h4*4+0].z += f4.z*w4.x; acc[h4*4+0].w += f4.w*w4.x;
      acc[h4*4+1].x += f4.x*w4.y; acc[h4*4+1].y += f4.y*w4.y; acc[h4*4+1].z += f4.z*w4.y; acc[h4*4+1].w += f4.w*w4.y;
      acc[h4*4+2].x += f4.x*w4.z; acc[h4*4+2].y += f4.y*w4.z; acc[h4*4+2].z += f4.z*w4.z; acc[h4*4+2].w += f4.w*w4.z;
      acc[h4*4+3].x += f4.x*w4.w; acc[h4*4+3].y += f4.y*w4.w; acc[h4*4+3].z += f4.z*w4.w; acc[h4*4+3].w += f4.w*w4.w;
    }
  }
#pragma unroll
  for (int h=0;h<16;h++)
    *(float4*)(part + (size_t)chunk*16384 + (size_t)h*1024 + d) = acc[h];
}

__global__ __launch_bounds__(256) void k_ctxred(float* __restrict__ ws){
  int b = blockIdx.x, tid = threadIdx.x;
  int br = (b >= 64) ? 1 : 0;
  int flat = (br ? b-64 : b)*256 + tid;
  const float* part = ws + (br ? W_PART_S : W_PART_G);
  int nc = br ? 64 : 256;
  float s = 0.f;
  for (int c=0;c<nc;c++) s += part[(size_t)c*16384 + flat];
  ws[(br ? W_CTX_S : W_CTX_G) + flat] = s;
}

// ---- o[h*64+c] = ctx[h] . Wv[:, 2048+h*64+c] + bv (atomic over d-chunks) ----
__global__ __launch_bounds__(64) void k_ohead(const float* __restrict__ cgw,
    const float* __restrict__ csw, const float* __restrict__ cgb,
    const float* __restrict__ csb, float* __restrict__ ws){
  int b = blockIdx.x, tid = threadIdx.x;
  int br = b >> 6; int rem = b & 63; int h = rem >> 2; int dch = rem & 3;
  const float* W  = br ? csw : cgw;
  const float* bi = br ? csb : cgb;
  const float* ctx = ws + (br ? W_CTX_S : W_CTX_G);
  float* o = ws + (br ? W_O_S : W_O_G);
  __shared__ float cx[256];
#pragma unroll
  for (int k2=0;k2<4;k2++) cx[tid*4+k2] = ctx[(size_t)h*1024 + dch*256 + tid*4 + k2];
  __syncthreads();
  float acc = (dch==0) ? bi[2048 + h*64 + tid] : 0.f;
  const float* wp = W + (size_t)(dch*256)*3072 + 2048 + h*64 + tid;
#pragma unroll 4
  for (int i=0;i<256;i++) acc += cx[i] * wp[(size_t)i*3072];
  atomicAdd(&o[h*64 + tid], acc);
}

extern "C" void kernel_launch(void* const* d_in, const int* in_sizes, int n_in,
                              void* d_out, int out_size, void* d_ws, size_t ws_size,
                              hipStream_t stream){
  (void)in_sizes; (void)n_in; (void)out_size; (void)ws_size;
  const float* fr    = (const float*)d_in[0];
  const float* qb    = (const float*)d_in[1];
  const float* re    = (const float*)d_in[2];
  const float* te    = (const float*)d_in[3];
  const float* ln1g  = (const float*)d_in[4];
  const float* ln1b  = (const float*)d_in[5];
  const float* ln2g  = (const float*)d_in[6];
  const float* ln2b  = (const float*)d_in[7];
  const float* ln3g  = (const float*)d_in[8];
  const float* ln3b  = (const float*)d_in[9];
  const float* sawin = (const float*)d_in[10];
  const float* sabin = (const float*)d_in[11];
  const float* sawout= (const float*)d_in[12];
  const float* sabout= (const float*)d_in[13];
  const float* cgwin = (const float*)d_in[14];
  const float* cgbin = (const float*)d_in[15];
  const float* cgwout= (const float*)d_in[16];
  const float* cgbout= (const float*)d_in[17];
  const float* cswin = (const float*)d_in[18];
  const float* csbin = (const float*)d_in[19];
  const float* cswout= (const float*)d_in[20];
  const float* csbout= (const float*)d_in[21];
  const float* fw1   = (const float*)d_in[22];
  const float* fb1   = (const float*)d_in[23];
  const float* fw2   = (const float*)d_in[24];
  const float* fb2   = (const float*)d_in[25];
  const float* outg  = (const float*)d_in[26];
  const float* outb  = (const float*)d_in[27];
  float* ws = (float*)d_ws;

  hipLaunchKernelGGL(k_stats,  dim3(512), dim3(256), 0, stream, fr, ws);
  hipLaunchKernelGGL(k_reduce, dim3(4),   dim3(256), 0, stream, ws, qb, re, te);
  hipLaunchKernelGGL(k_hist1,  dim3(128), dim3(256), 0, stream, ws);
  hipLaunchKernelGGL(k_find,   dim3(1),   dim3(1024),0, stream, ws, 0);
  hipLaunchKernelGGL(k_hist2,  dim3(128), dim3(256), 0, stream, ws);
  hipLaunchKernelGGL(k_find,   dim3(1),   dim3(1024),0, stream, ws, 1);
  hipLaunchKernelGGL(k_mark,   dim3(128), dim3(256), 0, stream, ws);
  hipLaunchKernelGGL(k_eqsel,  dim3(1),   dim3(256), 0, stream, ws);

  for (int li=0; li<NL; li++){
    const float* l_ln1g = ln1g + (size_t)li*DIM,  *l_ln1b = ln1b + (size_t)li*DIM;
    const float* l_ln2g = ln2g + (size_t)li*DIM,  *l_ln2b = ln2b + (size_t)li*DIM;
    const float* l_ln3g = ln3g + (size_t)li*DIM,  *l_ln3b = ln3b + (size_t)li*DIM;
    const float* l_sawin = sawin + (size_t)li*DIM*3072, *l_sabin = sabin + (size_t)li*3072;
    const float* l_sawout= sawout+ (size_t)li*DIM*DIM,  *l_sabout= sabout+ (size_t)li*DIM;
    const float* l_cgwin = cgwin + (size_t)li*DIM*3072, *l_cgbin = cgbin + (size_t)li*3072;
    const float* l_cgwout= cgwout+ (size_t)li*DIM*DIM,  *l_cgbout= cgbout+ (size_t)li*DIM;
    const float* l_cswin = cswin + (size_t)li*DIM*3072, *l_csbin = csbin + (size_t)li*3072;
    const float* l_cswout= cswout+ (size_t)li*DIM*DIM,  *l_csbout= csbout+ (size_t)li*DIM;
    const float* l_fw1 = fw1 + (size_t)li*DIM*4096, *l_fb1 = fb1 + (size_t)li*4096;
    const float* l_fw2 = fw2 + (size_t)li*4096*DIM, *l_fb2 = fb2 + (size_t)li*DIM;

    // LN1 (+zero qkv) ; self-attn qkv proj ; attn core ; out-proj (+residual into q)
    hipLaunchKernelGGL(k_ln, dim3(8),  dim3(256), 0, stream, ws+W_Q, l_ln1g, l_ln1b, ws+W_QLN1, 2, ws+W_QKV, 6144);
    hipLaunchKernelGGL(k_gemv, dim3(24,2), dim3(256), 1024*4, stream, ws+W_QLN1, 1024, l_sawin, 3072, l_sabin, ws+W_QKV, 3072, 1024, 3072, 128, 0);
    hipLaunchKernelGGL(k_attn_self, dim3(1), dim3(256), 0, stream, ws);
    hipLaunchKernelGGL(k_gemv, dim3(8,2), dim3(256), 1024*4, stream, ws+W_OSELF, 1024, l_sawout, 1024, l_sabout, ws+W_Q, 1024, 1024, 1024, 128, 0);

    // LN2 (+zero qp/es/o); query projections; qprojk; big passes
    hipLaunchKernelGGL(k_ln, dim3(7), dim3(256), 0, stream, ws+W_Q, l_ln2g, l_ln2b, ws+W_QLN2, 2, ws+W_QP_G, 4224);
    hipLaunchKernelGGL(k_gemv, dim3(8,1), dim3(256), 1024*4, stream, ws+W_QLN2,      1024, l_cgwin, 3072, l_cgbin, ws+W_QP_G, 1024, 1024, 1024, 128, 0);
    hipLaunchKernelGGL(k_gemv, dim3(8,1), dim3(256), 1024*4, stream, ws+W_QLN2+1024, 1024, l_cswin, 3072, l_csbin, ws+W_QP_S, 1024, 1024, 1024, 128, 0);
    hipLaunchKernelGGL(k_qproj, dim3(32), dim3(256), 0, stream, l_cgwin, l_cswin, ws);
    hipLaunchKernelGGL(k_scores, dim3(640), dim3(256), 0, stream, fr, ws);
    hipLaunchKernelGGL(k_ctx,    dim3(320), dim3(256), 0, stream, fr, ws);
    hipLaunchKernelGGL(k_ctxred, dim3(128), dim3(256), 0, stream, ws);
    hipLaunchKernelGGL(k_ohead,  dim3(128), dim3(64),  0, stream, l_cgwin, l_cswin, l_cgbin, l_csbin, ws);
    hipLaunchKernelGGL(k_gemv, dim3(8,1), dim3(256), 1024*4, stream, ws+W_O_G, 1024, l_cgwout, 1024, l_cgbout, ws+W_Q,      1024, 1024, 1024, 128, 0);
    hipLaunchKernelGGL(k_gemv, dim3(8,1), dim3(256), 1024*4, stream, ws+W_O_S, 1024, l_cswout, 1024, l_csbout, ws+W_Q+1024, 1024, 1024, 1024, 128, 0);

    // LN3 (+zero ffn_h); FFN1; FFN2 (GELU folded into input preload, +residual into q)
    hipLaunchKernelGGL(k_ln, dim3(10), dim3(256), 0, stream, ws+W_Q, l_ln3g, l_ln3b, ws+W_QLN3, 2, ws+W_FFNH, 8192);
    hipLaunchKernelGGL(k_gemv, dim3(32,2), dim3(256), 1024*4, stream, ws+W_QLN3, 1024, l_fw1, 4096, l_fb1, ws+W_FFNH, 4096, 1024, 4096, 128, 0);
    hipLaunchKernelGGL(k_gemv, dim3(16,2), dim3(256), 4096*4, stream, ws+W_FFNH, 4096, l_fw2, 1024, l_fb2, ws+W_Q, 1024, 4096, 1024, 256, 1);
  }
  hipLaunchKernelGGL(k_ln, dim3(2), dim3(256), 0, stream, ws+W_Q, outg, outb, (float*)d_out, 2, nullptr, 0);
}

// Round 4
// 1290.876 us; speedup vs baseline: 1.1980x; 1.1980x over previous
//
#include <hip/hip_runtime.h>
#include <math.h>

// DualTokenQFormer — algebraic reduction: single-query cross-attention means
// K/V projections collapse to  logits = frame @ (Wk_h @ q_h)  and
// O_h = (sum_j att_hj * frame_j) @ Wv_h.  Round 3: scores+ctx FUSED into one
// streaming pass (softmax division deferred to the chunk-reduce), bf16 partials,
// __expf, bigger GEMV grids, paired GEMV launches batched.

static constexpr int NT  = 32768;
static constexpr int DIM = 1024;
static constexpr int NL  = 2;

// workspace layout (float offsets) — total 6,576,128 floats = 26.3 MB (< proven 28.9)
static constexpr size_t W_SCORE=0, W_HIST1=32768, W_HIST2=98304, W_META=163840,
 W_EQIDX=163904, W_SALIDX=168000, W_STATS=180224,
 W_Q=1228800, W_QLN1=1230848, W_QLN2=1232896, W_QLN3=1234944,
 W_QKV=1236992, W_OSELF=1243136,
 W_QP_G=1245184, W_QP_S=1246208, W_O_G=1247232, W_O_S=1248256,   // contiguous 4096 zero range
 W_QPROJ_G=1249280, W_QPROJ_S=1265664,
 W_CTX_G=1282048, W_CTX_S=1298432, W_FFNH=1314816,
 W_ESP_G=1323008, W_ESP_S=1331200,
 W_PART_G=1333248,   // 512 chunks * 16384 bf16 (ushort)
 W_PART_S=5527552;   // 128 chunks * 16384 bf16

__device__ __forceinline__ float wred(float v){
#pragma unroll
  for (int off=1; off<64; off<<=1) v += __shfl_xor(v, off, 64);
  return v;
}
__device__ __forceinline__ float gelu_f(float x){
  return 0.5f*x*(1.0f + erff(x*0.70710678118654752440f));
}
__device__ __forceinline__ unsigned short bf16r(float x){
  unsigned u = __float_as_uint(x);
  u += 0x7FFFu + ((u>>16)&1u);
  return (unsigned short)(u>>16);
}
__device__ __forceinline__ float bf16f(unsigned short h){
  return __uint_as_float(((unsigned)h)<<16);
}

// ---- phase 0: per-row squared norm (saliency; monotone in norm), per-dim sum & max, zero hists ----
__global__ __launch_bounds__(256) void k_stats(const float* __restrict__ fr, float* __restrict__ ws){
  int b = blockIdx.x, tid = threadIdx.x, wv = tid>>6, l = tid&63;
  ((unsigned*)ws)[W_HIST1 + (size_t)b*256 + tid] = 0u;     // 512*256 covers hist1+hist2
  if (b==0 && tid<64) ((unsigned*)ws)[W_META + tid] = 0u;
  float ssum[16], smx[16];
#pragma unroll
  for (int i=0;i<16;i++){ ssum[i]=0.f; smx[i]=-3.402823466e38f; }
  int row0 = b*64 + wv*16;
#pragma unroll 2
  for (int r=0;r<16;r++){
    const float* rp = fr + (size_t)(row0+r)*DIM;
    float nrm = 0.f;
#pragma unroll
    for (int p=0;p<4;p++){
      float4 v = *(const float4*)(rp + p*256 + l*4);
      ssum[p*4+0]+=v.x; ssum[p*4+1]+=v.y; ssum[p*4+2]+=v.z; ssum[p*4+3]+=v.w;
      smx[p*4+0]=fmaxf(smx[p*4+0],v.x); smx[p*4+1]=fmaxf(smx[p*4+1],v.y);
      smx[p*4+2]=fmaxf(smx[p*4+2],v.z); smx[p*4+3]=fmaxf(smx[p*4+3],v.w);
      nrm += v.x*v.x + v.y*v.y + v.z*v.z + v.w*v.w;
    }
    nrm = wred(nrm);
    if (l==0) ws[W_SCORE + row0 + r] = nrm;   // squared norm: same top-k set
  }
  __shared__ float lsum[1024], lmax[1024];
  for (int w=0; w<4; w++){
    if (wv==w){
#pragma unroll
      for (int p=0;p<4;p++)
#pragma unroll
        for (int i=0;i<4;i++){
          int d = p*256 + l*4 + i;
          if (w==0){ lsum[d]=ssum[p*4+i]; lmax[d]=smx[p*4+i]; }
          else     { lsum[d]+=ssum[p*4+i]; lmax[d]=fmaxf(lmax[d],smx[p*4+i]); }
        }
    }
    __syncthreads();
  }
  float* st = ws + W_STATS + (size_t)b*2048;
  for (int i=tid;i<1024;i+=256){ st[i]=lsum[i]; st[1024+i]=lmax[i]; }
}

// ---- reduce stats -> q init ----
__global__ __launch_bounds__(256) void k_reduce(float* __restrict__ ws,
    const float* __restrict__ qb, const float* __restrict__ re, const float* __restrict__ te){
  int d = blockIdx.x*256 + threadIdx.x;
  const float* st = ws + W_STATS;
  float s=0.f, m=-3.402823466e38f;
  for (int c=0;c<512;c++){ s += st[(size_t)c*2048 + d]; m = fmaxf(m, st[(size_t)c*2048 + 1024 + d]); }
  float mean = s * (1.0f/32768.0f);
  ws[W_Q + d]        = mean + qb[d]        + re[d]        + te[d];
  ws[W_Q + 1024 + d] = m    + qb[1024 + d] + re[1024 + d] + te[d];
}

// ---- radix-select top-8192 on f32 score bits (non-negative => uint-monotonic) ----
__global__ void k_hist1(float* ws){
  int i = blockIdx.x*256 + threadIdx.x;
  unsigned u = __float_as_uint(ws[W_SCORE + i]);
  atomicAdd(((unsigned*)ws) + W_HIST1 + (u>>16), 1u);
}
__global__ void k_hist2(float* ws){
  unsigned* meta = (unsigned*)ws + W_META;
  int i = blockIdx.x*256 + threadIdx.x;
  unsigned u = __float_as_uint(ws[W_SCORE + i]);
  if ((u>>16) == meta[0]) atomicAdd(((unsigned*)ws) + W_HIST2 + (u & 0xFFFFu), 1u);
}
__global__ __launch_bounds__(1024) void k_find(float* ws, int which){
  unsigned* hist = (unsigned*)ws + (which ? W_HIST2 : W_HIST1);
  unsigned* meta = (unsigned*)ws + W_META;
  __shared__ unsigned ls[1024];
  int t = threadIdx.x;
  unsigned kk = which ? (8192u - meta[1]) : 8192u;
  unsigned s = 0;
  for (int i=0;i<64;i++) s += hist[t*64 + i];
  ls[t] = s; __syncthreads();
  for (int off=1; off<1024; off<<=1){
    unsigned v = ls[t] + ((t+off<1024)? ls[t+off] : 0u);
    __syncthreads(); ls[t] = v; __syncthreads();
  }
  unsigned suf_in = ls[t];
  unsigned suf_ex = (t<1023) ? ls[t+1] : 0u;
  if (suf_in >= kk && suf_ex < kk){
    unsigned run = suf_ex;
    for (int i=63;i>=0;i--){
      unsigned c = hist[t*64+i];
      if (run + c >= kk){
        if (!which){ meta[0] = (unsigned)(t*64+i); meta[1] = run; }
        else { meta[2] = (meta[0]<<16) | (unsigned)(t*64+i); meta[3] = kk - run; }
        break;
      }
      run += c;
    }
  }
}
__global__ void k_mark(float* ws){
  unsigned* meta = (unsigned*)ws + W_META;
  unsigned* sal  = (unsigned*)ws + W_SALIDX;
  unsigned* eq   = (unsigned*)ws + W_EQIDX;
  int i = blockIdx.x*256 + threadIdx.x;
  unsigned u = __float_as_uint(ws[W_SCORE + i]);
  unsigned U = meta[2];
  if (u > U){ unsigned p = atomicAdd(&meta[5], 1u); sal[p] = (unsigned)i; }
  else if (u == U){ unsigned p = atomicAdd(&meta[4], 1u); if (p < 4096u) eq[p] = (unsigned)i; }
}
__global__ __launch_bounds__(256) void k_eqsel(float* ws){
  unsigned* meta = (unsigned*)ws + W_META;
  unsigned* sal  = (unsigned*)ws + W_SALIDX;
  unsigned* eq   = (unsigned*)ws + W_EQIDX;
  unsigned n = meta[4]; if (n > 4096u) n = 4096u;
  unsigned r = meta[3];
  for (unsigned e = threadIdx.x; e < n; e += 256){
    unsigned me = eq[e];
    unsigned rank = 0;
    for (unsigned j=0;j<n;j++) rank += (eq[j] < me) ? 1u : 0u;
    if (rank < r){ unsigned p = atomicAdd(&meta[5], 1u); sal[p] = me; }
  }
}

// ---- LayerNorm rows of 1024 (+ optional zero of a scratch range) ----
__global__ __launch_bounds__(256) void k_ln(const float* __restrict__ in,
    const float* __restrict__ g, const float* __restrict__ bt, float* __restrict__ out,
    int n_rows, float* zptr, int zlen){
  int b = blockIdx.x, tid = threadIdx.x, wv = tid>>6;
  if (b >= n_rows){
    int zb = b - n_rows;
    int i0 = zb*1024 + tid;
#pragma unroll
    for (int k=0;k<4;k++){ int i = i0 + k*256; if (i < zlen) zptr[i] = 0.f; }
    return;
  }
  const float* x = in + (size_t)b*1024;
  float4 v = *(const float4*)(x + tid*4);
  float s  = v.x+v.y+v.z+v.w;
  float s2 = v.x*v.x+v.y*v.y+v.z*v.z+v.w*v.w;
  s = wred(s); s2 = wred(s2);
  __shared__ float rs[4], rq[4];
  if ((tid&63)==0){ rs[wv]=s; rq[wv]=s2; }
  __syncthreads();
  s = rs[0]+rs[1]+rs[2]+rs[3]; s2 = rq[0]+rq[1]+rq[2]+rq[3];
  float m = s * (1.0f/1024.0f);
  float var = s2 * (1.0f/1024.0f) - m*m;
  float rstd = rsqrtf(var + 1e-5f);
  float4 gv = *(const float4*)(g + tid*4);
  float4 bv = *(const float4*)(bt + tid*4);
  float4 o;
  o.x = (v.x-m)*rstd*gv.x + bv.x; o.y = (v.y-m)*rstd*gv.y + bv.y;
  o.z = (v.z-m)*rstd*gv.z + bv.z; o.w = (v.w-m)*rstd*gv.w + bv.w;
  *(float4*)(out + (size_t)b*1024 + tid*4) = o;
}

// ---- K-chunked GEMV, f32 atomic partials; bias in chunk 0; optional GELU on input preload ----
__global__ __launch_bounds__(256) void k_gemv(const float* __restrict__ in, int in_stride,
    const float* __restrict__ W, int ldw, const float* __restrict__ bias,
    float* __restrict__ out, int out_stride, int K, int n_out, int kchunk, int gelu_in){
  extern __shared__ float sin_[];
  int tid = threadIdx.x;
  const float* inr = in + (size_t)blockIdx.y * in_stride;
  for (int i = tid*4; i < K; i += 1024){
    float4 v = *(const float4*)(inr + i);
    if (gelu_in){ v.x=gelu_f(v.x); v.y=gelu_f(v.y); v.z=gelu_f(v.z); v.w=gelu_f(v.w); }
    *(float4*)(sin_ + i) = v;
  }
  __syncthreads();
  int wid = blockIdx.x*4 + (tid>>6);
  int l = tid & 63;
  int n_os = n_out >> 8;
  int os  = (wid % n_os) * 256;
  int kch = wid / n_os;
  int f0 = kch * kchunk;
  int o = os + l*4;
  float a0=0,a1=0,a2=0,a3=0;
  if (kch==0 && bias){ a0=bias[o]; a1=bias[o+1]; a2=bias[o+2]; a3=bias[o+3]; }
  const float* Wp = W + (size_t)f0*ldw + o;
#pragma unroll 8
  for (int f=0; f<kchunk; f++){
    float sv = sin_[f0+f];
    float4 w4 = *(const float4*)(Wp + (size_t)f*ldw);
    a0 += sv*w4.x; a1 += sv*w4.y; a2 += sv*w4.z; a3 += sv*w4.w;
  }
  float* op = out + (size_t)blockIdx.y*out_stride + o;
  atomicAdd(op+0,a0); atomicAdd(op+1,a1); atomicAdd(op+2,a2); atomicAdd(op+3,a3);
}

// ---- paired single-row GEMV (two independent {in,W,bias,out} sets; blockIdx.y selects) ----
__global__ __launch_bounds__(256) void k_gemv_pair(
    const float* __restrict__ in0, const float* __restrict__ in1,
    const float* __restrict__ W0,  const float* __restrict__ W1,
    const float* __restrict__ b0,  const float* __restrict__ b1,
    float* __restrict__ out0, float* __restrict__ out1,
    int ldw, int K, int n_out, int kchunk){
  extern __shared__ float sin_[];
  int tid = threadIdx.x;
  int item = blockIdx.y;
  const float* inr = item ? in1 : in0;
  const float* W   = item ? W1  : W0;
  const float* bias= item ? b1  : b0;
  float* out       = item ? out1: out0;
  for (int i = tid*4; i < K; i += 1024)
    *(float4*)(sin_ + i) = *(const float4*)(inr + i);
  __syncthreads();
  int wid = blockIdx.x*4 + (tid>>6);
  int l = tid & 63;
  int n_os = n_out >> 8;
  int os  = (wid % n_os) * 256;
  int kch = wid / n_os;
  int f0 = kch * kchunk;
  int o = os + l*4;
  float a0=0,a1=0,a2=0,a3=0;
  if (kch==0){ a0=bias[o]; a1=bias[o+1]; a2=bias[o+2]; a3=bias[o+3]; }
  const float* Wp = W + (size_t)f0*ldw + o;
#pragma unroll 8
  for (int f=0; f<kchunk; f++){
    float sv = sin_[f0+f];
    float4 w4 = *(const float4*)(Wp + (size_t)f*ldw);
    a0 += sv*w4.x; a1 += sv*w4.y; a2 += sv*w4.z; a3 += sv*w4.w;
  }
  float* op = out + o;
  atomicAdd(op+0,a0); atomicAdd(op+1,a1); atomicAdd(op+2,a2); atomicAdd(op+3,a3);
}

// ---- 2-token self-attention core (qkv -> o), 16 heads ----
__global__ __launch_bounds__(256) void k_attn_self(float* __restrict__ ws){
  const float* qkv = ws + W_QKV;
  float* o = ws + W_OSELF;
  int tid = threadIdx.x, wv = tid>>6, l = tid&63;
#pragma unroll
  for (int p=0;p<4;p++){
    int off = (wv + p*4)*64 + l;
    float qa = qkv[off],        qb = qkv[3072+off];
    float ka = qkv[1024+off],   kb = qkv[3072+1024+off];
    float va = qkv[2048+off],   vb = qkv[3072+2048+off];
    float s00 = wred(qa*ka)*0.125f, s01 = wred(qa*kb)*0.125f;
    float s10 = wred(qb*ka)*0.125f, s11 = wred(qb*kb)*0.125f;
    float m0 = fmaxf(s00,s01); float e00=__expf(s00-m0), e01=__expf(s01-m0); float r0=1.f/(e00+e01);
    float m1 = fmaxf(s10,s11); float e10=__expf(s10-m1), e11=__expf(s11-m1); float r1=1.f/(e10+e11);
    o[off]        = (e00*va + e01*vb)*r0;
    o[1024 + off] = (e10*va + e11*vb)*r1;
  }
}

// ---- qprojk[h][d] = (Wk[d, h-slice] . qp[h-slice]) / 8 for both branches ----
__global__ __launch_bounds__(256) void k_qproj(const float* __restrict__ cgw,
    const float* __restrict__ csw, float* __restrict__ ws){
  int br = blockIdx.x >> 4, h = blockIdx.x & 15, tid = threadIdx.x;
  const float* W  = br ? csw : cgw;
  const float* qp = ws + (br ? W_QP_S : W_QP_G);
  float* qpr      = ws + (br ? W_QPROJ_S : W_QPROJ_G);
  __shared__ float qs[64];
  if (tid < 64) qs[tid] = qp[h*64 + tid];
  __syncthreads();
#pragma unroll
  for (int dd=0; dd<4; dd++){
    int d = tid*4 + dd;
    const float* wr = W + (size_t)d*3072 + 1024 + h*64;
    float acc = 0.f;
#pragma unroll
    for (int c4=0;c4<16;c4++){
      float4 w4 = *(const float4*)(wr + c4*4);
      acc += w4.x*qs[c4*4] + w4.y*qs[c4*4+1] + w4.z*qs[c4*4+2] + w4.w*qs[c4*4+3];
    }
    qpr[h*1024 + d] = acc * 0.125f;
  }
}

// ---- FUSED cross-attention pass: per 64-row chunk, per wave (4 heads):
//      s_h = row . qproj_h ; w = exp(s) ; acc_h += w*row ; es_h += w.
//      Unnormalized bf16 partials + f32 es per chunk; division deferred to k_ctxred.
//      Global: blocks 0..511 (32768 rows). Salient: 512..639 (8192 gathered rows). ----
__global__ __launch_bounds__(256,2) void k_fused(const float* __restrict__ fr, float* __restrict__ ws){
  int b = blockIdx.x, tid = threadIdx.x, wv = tid>>6, l = tid&63;
  int br = (b >= 512) ? 1 : 0;
  int chunk = br ? b - 512 : b;
  __shared__ unsigned idx[64];
  if (br && tid < 64) idx[tid] = ((unsigned*)ws)[W_SALIDX + chunk*64 + tid];
  __syncthreads();
  const float* qpr = ws + (br ? W_QPROJ_S : W_QPROJ_G);
  int hb = wv*4;
  float4 qv[4][4];
#pragma unroll
  for (int h=0;h<4;h++)
#pragma unroll
    for (int p=0;p<4;p++)
      qv[h][p] = *(const float4*)(qpr + (size_t)(hb+h)*1024 + p*256 + l*4);
  float4 acc[4][4];
#pragma unroll
  for (int h=0;h<4;h++)
#pragma unroll
    for (int p=0;p<4;p++) acc[h][p] = make_float4(0.f,0.f,0.f,0.f);
  float es0=0.f, es1=0.f, es2=0.f, es3=0.f;

  int j0 = br ? (int)idx[0] : chunk*64;
  const float* rp = fr + (size_t)j0*DIM + l*4;
  float4 c0 = *(const float4*)(rp);
  float4 c1 = *(const float4*)(rp + 256);
  float4 c2 = *(const float4*)(rp + 512);
  float4 c3 = *(const float4*)(rp + 768);

  for (int r=0; r<64; r++){
    float4 n0,n1,n2,n3;
    if (r < 63){
      int jn = br ? (int)idx[r+1] : chunk*64 + r + 1;
      const float* rn = fr + (size_t)jn*DIM + l*4;
      n0 = *(const float4*)(rn);       n1 = *(const float4*)(rn + 256);
      n2 = *(const float4*)(rn + 512); n3 = *(const float4*)(rn + 768);
    }
    float s[4];
#pragma unroll
    for (int h=0;h<4;h++){
      s[h] = c0.x*qv[h][0].x + c0.y*qv[h][0].y + c0.z*qv[h][0].z + c0.w*qv[h][0].w
           + c1.x*qv[h][1].x + c1.y*qv[h][1].y + c1.z*qv[h][1].z + c1.w*qv[h][1].w
           + c2.x*qv[h][2].x + c2.y*qv[h][2].y + c2.z*qv[h][2].z + c2.w*qv[h][2].w
           + c3.x*qv[h][3].x + c3.y*qv[h][3].y + c3.z*qv[h][3].z + c3.w*qv[h][3].w;
      s[h] = wred(s[h]);            // butterfly: every lane holds the full sum
    }
    float w0 = __expf(s[0]), w1 = __expf(s[1]), w2 = __expf(s[2]), w3 = __expf(s[3]);
    es0 += w0; es1 += w1; es2 += w2; es3 += w3;
#pragma unroll
    for (int p=0;p<4;p++){
      float4 cp = (p==0)?c0:(p==1)?c1:(p==2)?c2:c3;
      acc[0][p].x += w0*cp.x; acc[0][p].y += w0*cp.y; acc[0][p].z += w0*cp.z; acc[0][p].w += w0*cp.w;
      acc[1][p].x += w1*cp.x; acc[1][p].y += w1*cp.y; acc[1][p].z += w1*cp.z; acc[1][p].w += w1*cp.w;
      acc[2][p].x += w2*cp.x; acc[2][p].y += w2*cp.y; acc[2][p].z += w2*cp.z; acc[2][p].w += w2*cp.w;
      acc[3][p].x += w3*cp.x; acc[3][p].y += w3*cp.y; acc[3][p].z += w3*cp.z; acc[3][p].w += w3*cp.w;
    }
    if (r < 63){ c0=n0; c1=n1; c2=n2; c3=n3; }
  }
  // write bf16 partials (unnormalized) + f32 es
  unsigned short* pb = (unsigned short*)(ws + (br ? W_PART_S : W_PART_G));
#pragma unroll
  for (int h=0;h<4;h++)
#pragma unroll
    for (int p=0;p<4;p++){
      ushort4 u;
      u.x = bf16r(acc[h][p].x); u.y = bf16r(acc[h][p].y);
      u.z = bf16r(acc[h][p].z); u.w = bf16r(acc[h][p].w);
      *(ushort4*)(pb + (size_t)chunk*16384 + (size_t)(hb+h)*1024 + p*256 + l*4) = u;
    }
  if (l == 0){
    float* esp = ws + (br ? W_ESP_S : W_ESP_G) + (size_t)chunk*16 + hb;
    esp[0]=es0; esp[1]=es1; esp[2]=es2; esp[3]=es3;
  }
}

// ---- reduce chunks: ctx[h][d] = sum_c part / sum_c es ----
__global__ __launch_bounds__(256) void k_ctxred(float* __restrict__ ws){
  int b = blockIdx.x, tid = threadIdx.x;
  int br = (b >= 64) ? 1 : 0;
  int flat = (br ? b-64 : b)*256 + tid;
  int h = flat >> 10;
  const unsigned short* pb = (const unsigned short*)(ws + (br ? W_PART_S : W_PART_G));
  const float* esp = ws + (br ? W_ESP_S : W_ESP_G);
  int nc = br ? 128 : 512;
  float den = 0.f;
  for (int c=0;c<nc;c++) den += esp[(size_t)c*16 + h];
  float s = 0.f;
  for (int c=0;c<nc;c++) s += bf16f(pb[(size_t)c*16384 + flat]);
  ws[(br ? W_CTX_S : W_CTX_G) + flat] = s / den;
}

// ---- o[h*64+c] = ctx[h] . Wv[:, 2048+h*64+c] + bv (atomic over d-chunks) ----
__global__ __launch_bounds__(64) void k_ohead(const float* __restrict__ cgw,
    const float* __restrict__ csw, const float* __restrict__ cgb,
    const float* __restrict__ csb, float* __restrict__ ws){
  int b = blockIdx.x, tid = threadIdx.x;
  int br = b >> 6; int rem = b & 63; int h = rem >> 2; int dch = rem & 3;
  const float* W  = br ? csw : cgw;
  const float* bi = br ? csb : cgb;
  const float* ctx = ws + (br ? W_CTX_S : W_CTX_G);
  float* o = ws + (br ? W_O_S : W_O_G);
  __shared__ float cx[256];
#pragma unroll
  for (int k2=0;k2<4;k2++) cx[tid*4+k2] = ctx[(size_t)h*1024 + dch*256 + tid*4 + k2];
  __syncthreads();
  float acc = (dch==0) ? bi[2048 + h*64 + tid] : 0.f;
  const float* wp = W + (size_t)(dch*256)*3072 + 2048 + h*64 + tid;
#pragma unroll 4
  for (int i=0;i<256;i++) acc += cx[i] * wp[(size_t)i*3072];
  atomicAdd(&o[h*64 + tid], acc);
}

extern "C" void kernel_launch(void* const* d_in, const int* in_sizes, int n_in,
                              void* d_out, int out_size, void* d_ws, size_t ws_size,
                              hipStream_t stream){
  (void)in_sizes; (void)n_in; (void)out_size; (void)ws_size; (void)NT;
  const float* fr    = (const float*)d_in[0];
  const float* qb    = (const float*)d_in[1];
  const float* re    = (const float*)d_in[2];
  const float* te    = (const float*)d_in[3];
  const float* ln1g  = (const float*)d_in[4];
  const float* ln1b  = (const float*)d_in[5];
  const float* ln2g  = (const float*)d_in[6];
  const float* ln2b  = (const float*)d_in[7];
  const float* ln3g  = (const float*)d_in[8];
  const float* ln3b  = (const float*)d_in[9];
  const float* sawin = (const float*)d_in[10];
  const float* sabin = (const float*)d_in[11];
  const float* sawout= (const float*)d_in[12];
  const float* sabout= (const float*)d_in[13];
  const float* cgwin = (const float*)d_in[14];
  const float* cgbin = (const float*)d_in[15];
  const float* cgwout= (const float*)d_in[16];
  const float* cgbout= (const float*)d_in[17];
  const float* cswin = (const float*)d_in[18];
  const float* csbin = (const float*)d_in[19];
  const float* cswout= (const float*)d_in[20];
  const float* csbout= (const float*)d_in[21];
  const float* fw1   = (const float*)d_in[22];
  const float* fb1   = (const float*)d_in[23];
  const float* fw2   = (const float*)d_in[24];
  const float* fb2   = (const float*)d_in[25];
  const float* outg  = (const float*)d_in[26];
  const float* outb  = (const float*)d_in[27];
  float* ws = (float*)d_ws;

  hipLaunchKernelGGL(k_stats,  dim3(512), dim3(256), 0, stream, fr, ws);
  hipLaunchKernelGGL(k_reduce, dim3(4),   dim3(256), 0, stream, ws, qb, re, te);
  hipLaunchKernelGGL(k_hist1,  dim3(128), dim3(256), 0, stream, ws);
  hipLaunchKernelGGL(k_find,   dim3(1),   dim3(1024),0, stream, ws, 0);
  hipLaunchKernelGGL(k_hist2,  dim3(128), dim3(256), 0, stream, ws);
  hipLaunchKernelGGL(k_find,   dim3(1),   dim3(1024),0, stream, ws, 1);
  hipLaunchKernelGGL(k_mark,   dim3(128), dim3(256), 0, stream, ws);
  hipLaunchKernelGGL(k_eqsel,  dim3(1),   dim3(256), 0, stream, ws);

  for (int li=0; li<NL; li++){
    const float* l_ln1g = ln1g + (size_t)li*DIM,  *l_ln1b = ln1b + (size_t)li*DIM;
    const float* l_ln2g = ln2g + (size_t)li*DIM,  *l_ln2b = ln2b + (size_t)li*DIM;
    const float* l_ln3g = ln3g + (size_t)li*DIM,  *l_ln3b = ln3b + (size_t)li*DIM;
    const float* l_sawin = sawin + (size_t)li*DIM*3072, *l_sabin = sabin + (size_t)li*3072;
    const float* l_sawout= sawout+ (size_t)li*DIM*DIM,  *l_sabout= sabout+ (size_t)li*DIM;
    const float* l_cgwin = cgwin + (size_t)li*DIM*3072, *l_cgbin = cgbin + (size_t)li*3072;
    const float* l_cgwout= cgwout+ (size_t)li*DIM*DIM,  *l_cgbout= cgbout+ (size_t)li*DIM;
    const float* l_cswin = cswin + (size_t)li*DIM*3072, *l_csbin = csbin + (size_t)li*3072;
    const float* l_cswout= cswout+ (size_t)li*DIM*DIM,  *l_csbout= csbout+ (size_t)li*DIM;
    const float* l_fw1 = fw1 + (size_t)li*DIM*4096, *l_fb1 = fb1 + (size_t)li*4096;
    const float* l_fw2 = fw2 + (size_t)li*4096*DIM, *l_fb2 = fb2 + (size_t)li*DIM;

    // self-attention: LN1(+zero qkv) ; qkv proj ; attn core ; out-proj (+residual)
    hipLaunchKernelGGL(k_ln, dim3(8),  dim3(256), 0, stream, ws+W_Q, l_ln1g, l_ln1b, ws+W_QLN1, 2, ws+W_QKV, 6144);
    hipLaunchKernelGGL(k_gemv, dim3(96,2), dim3(256), 1024*4, stream, ws+W_QLN1, 1024, l_sawin, 3072, l_sabin, ws+W_QKV, 3072, 1024, 3072, 32, 0);
    hipLaunchKernelGGL(k_attn_self, dim3(1), dim3(256), 0, stream, ws);
    hipLaunchKernelGGL(k_gemv, dim3(64,2), dim3(256), 1024*4, stream, ws+W_OSELF, 1024, l_sawout, 1024, l_sabout, ws+W_Q, 1024, 1024, 1024, 16, 0);

    // cross-attention: LN2(+zero qp/o) ; q projections (paired) ; qprojk ; fused pass ; reduce ; V/out proj
    hipLaunchKernelGGL(k_ln, dim3(6), dim3(256), 0, stream, ws+W_Q, l_ln2g, l_ln2b, ws+W_QLN2, 2, ws+W_QP_G, 4096);
    hipLaunchKernelGGL(k_gemv_pair, dim3(64,2), dim3(256), 1024*4, stream,
                       ws+W_QLN2, ws+W_QLN2+1024, l_cgwin, l_cswin, l_cgbin, l_csbin,
                       ws+W_QP_G, ws+W_QP_S, 3072, 1024, 1024, 16);
    hipLaunchKernelGGL(k_qproj, dim3(32), dim3(256), 0, stream, l_cgwin, l_cswin, ws);
    hipLaunchKernelGGL(k_fused, dim3(640), dim3(256), 0, stream, fr, ws);
    hipLaunchKernelGGL(k_ctxred, dim3(128), dim3(256), 0, stream, ws);
    hipLaunchKernelGGL(k_ohead,  dim3(128), dim3(64),  0, stream, l_cgwin, l_cswin, l_cgbin, l_csbin, ws);
    hipLaunchKernelGGL(k_gemv_pair, dim3(64,2), dim3(256), 1024*4, stream,
                       ws+W_O_G, ws+W_O_S, l_cgwout, l_cswout, l_cgbout, l_csbout,
                       ws+W_Q, ws+W_Q+1024, 1024, 1024, 1024, 16);

    // FFN: LN3(+zero ffn_h) ; FFN1 ; FFN2 (GELU in preload, +residual)
    hipLaunchKernelGGL(k_ln, dim3(10), dim3(256), 0, stream, ws+W_Q, l_ln3g, l_ln3b, ws+W_QLN3, 2, ws+W_FFNH, 8192);
    hipLaunchKernelGGL(k_gemv, dim3(128,2), dim3(256), 1024*4, stream, ws+W_QLN3, 1024, l_fw1, 4096, l_fb1, ws+W_FFNH, 4096, 1024, 4096, 32, 0);
    hipLaunchKernelGGL(k_gemv, dim3(128,2), dim3(256), 4096*4, stream, ws+W_FFNH, 4096, l_fw2, 1024, l_fb2, ws+W_Q, 1024, 4096, 1024, 32, 1);
  }
  hipLaunchKernelGGL(k_ln, dim3(2), dim3(256), 0, stream, ws+W_Q, outg, outb, (float*)d_out, 2, nullptr, 0);
}

// Round 5
// 841.720 us; speedup vs baseline: 1.8373x; 1.5336x over previous
//
#include <hip/hip_runtime.h>
#include <math.h>

// DualTokenQFormer — algebraic reduction: single-query cross-attention means
// K/V projections collapse to  logits = frame @ (Wk_h @ q_h)  and
// O_h = (sum_j att_hj * frame_j) @ Wv_h.
// Round 5: replace the latency-bound k_ctxred (193us, 512-deep strided walk) with a
// parallel 2-D chunk-group reduction (k_psum) + normalization folded into k_ohead;
// k_fused rebuilt as 512-thread / 2-heads-per-wave (no VGPR spill risk); k_ohead 4x waves.

static constexpr int NT  = 32768;
static constexpr int DIM = 1024;
static constexpr int NL  = 2;

// workspace layout (float offsets) — total 6,576,256 floats = 26.3 MB
static constexpr size_t W_SCORE=0, W_HIST1=32768, W_HIST2=98304, W_META=163840,
 W_EQIDX=163904, W_SALIDX=168000, W_STATS=180224,
 W_Q=1228800, W_QLN1=1230848, W_QLN2=1232896, W_QLN3=1234944,
 W_QKV=1236992, W_OSELF=1243136,
 // contiguous zero-range (36992 floats) starts here:
 W_QP_G=1245184, W_QP_S=1246208, W_O_G=1247232, W_O_S=1248256,
 W_ES_G=1249280, W_ES_S=1249344, W_CTX_G=1249408, W_CTX_S=1265792,
 // end zero-range at 1282176
 W_ESP_G=1282176, W_ESP_S=1290368,
 W_QPROJ_G=1292416, W_QPROJ_S=1308800, W_FFNH=1325184,
 W_PART_G=1333376,   // 512 chunks * 16384 bf16 (ushort) = 4,194,304 floats
 W_PART_S=5527680;   // 128 chunks * 16384 bf16 = 1,048,576 floats

__device__ __forceinline__ float wred(float v){
#pragma unroll
  for (int off=1; off<64; off<<=1) v += __shfl_xor(v, off, 64);
  return v;
}
__device__ __forceinline__ float gelu_f(float x){
  return 0.5f*x*(1.0f + erff(x*0.70710678118654752440f));
}
__device__ __forceinline__ unsigned short bf16r(float x){
  unsigned u = __float_as_uint(x);
  u += 0x7FFFu + ((u>>16)&1u);
  return (unsigned short)(u>>16);
}
__device__ __forceinline__ float bf16f(unsigned short h){
  return __uint_as_float(((unsigned)h)<<16);
}

// ---- phase 0: per-row squared norm (saliency), per-dim sum & max, zero hists ----
__global__ __launch_bounds__(256) void k_stats(const float* __restrict__ fr, float* __restrict__ ws){
  int b = blockIdx.x, tid = threadIdx.x, wv = tid>>6, l = tid&63;
  ((unsigned*)ws)[W_HIST1 + (size_t)b*256 + tid] = 0u;     // 512*256 covers hist1+hist2
  if (b==0 && tid<64) ((unsigned*)ws)[W_META + tid] = 0u;
  float ssum[16], smx[16];
#pragma unroll
  for (int i=0;i<16;i++){ ssum[i]=0.f; smx[i]=-3.402823466e38f; }
  int row0 = b*64 + wv*16;
#pragma unroll 2
  for (int r=0;r<16;r++){
    const float* rp = fr + (size_t)(row0+r)*DIM;
    float nrm = 0.f;
#pragma unroll
    for (int p=0;p<4;p++){
      float4 v = *(const float4*)(rp + p*256 + l*4);
      ssum[p*4+0]+=v.x; ssum[p*4+1]+=v.y; ssum[p*4+2]+=v.z; ssum[p*4+3]+=v.w;
      smx[p*4+0]=fmaxf(smx[p*4+0],v.x); smx[p*4+1]=fmaxf(smx[p*4+1],v.y);
      smx[p*4+2]=fmaxf(smx[p*4+2],v.z); smx[p*4+3]=fmaxf(smx[p*4+3],v.w);
      nrm += v.x*v.x + v.y*v.y + v.z*v.z + v.w*v.w;
    }
    nrm = wred(nrm);
    if (l==0) ws[W_SCORE + row0 + r] = nrm;   // squared norm: same top-k set
  }
  __shared__ float lsum[1024], lmax[1024];
  for (int w=0; w<4; w++){
    if (wv==w){
#pragma unroll
      for (int p=0;p<4;p++)
#pragma unroll
        for (int i=0;i<4;i++){
          int d = p*256 + l*4 + i;
          if (w==0){ lsum[d]=ssum[p*4+i]; lmax[d]=smx[p*4+i]; }
          else     { lsum[d]+=ssum[p*4+i]; lmax[d]=fmaxf(lmax[d],smx[p*4+i]); }
        }
    }
    __syncthreads();
  }
  float* st = ws + W_STATS + (size_t)b*2048;
  for (int i=tid;i<1024;i+=256){ st[i]=lsum[i]; st[1024+i]=lmax[i]; }
}

// ---- reduce stats -> q init ----
__global__ __launch_bounds__(256) void k_reduce(float* __restrict__ ws,
    const float* __restrict__ qb, const float* __restrict__ re, const float* __restrict__ te){
  int d = blockIdx.x*256 + threadIdx.x;
  const float* st = ws + W_STATS;
  float s=0.f, m=-3.402823466e38f;
  for (int c=0;c<512;c++){ s += st[(size_t)c*2048 + d]; m = fmaxf(m, st[(size_t)c*2048 + 1024 + d]); }
  float mean = s * (1.0f/32768.0f);
  ws[W_Q + d]        = mean + qb[d]        + re[d]        + te[d];
  ws[W_Q + 1024 + d] = m    + qb[1024 + d] + re[1024 + d] + te[d];
}

// ---- radix-select top-8192 on f32 score bits ----
__global__ void k_hist1(float* ws){
  int i = blockIdx.x*256 + threadIdx.x;
  unsigned u = __float_as_uint(ws[W_SCORE + i]);
  atomicAdd(((unsigned*)ws) + W_HIST1 + (u>>16), 1u);
}
__global__ void k_hist2(float* ws){
  unsigned* meta = (unsigned*)ws + W_META;
  int i = blockIdx.x*256 + threadIdx.x;
  unsigned u = __float_as_uint(ws[W_SCORE + i]);
  if ((u>>16) == meta[0]) atomicAdd(((unsigned*)ws) + W_HIST2 + (u & 0xFFFFu), 1u);
}
__global__ __launch_bounds__(1024) void k_find(float* ws, int which){
  unsigned* hist = (unsigned*)ws + (which ? W_HIST2 : W_HIST1);
  unsigned* meta = (unsigned*)ws + W_META;
  __shared__ unsigned ls[1024];
  int t = threadIdx.x;
  unsigned kk = which ? (8192u - meta[1]) : 8192u;
  unsigned s = 0;
  for (int i=0;i<64;i++) s += hist[t*64 + i];
  ls[t] = s; __syncthreads();
  for (int off=1; off<1024; off<<=1){
    unsigned v = ls[t] + ((t+off<1024)? ls[t+off] : 0u);
    __syncthreads(); ls[t] = v; __syncthreads();
  }
  unsigned suf_in = ls[t];
  unsigned suf_ex = (t<1023) ? ls[t+1] : 0u;
  if (suf_in >= kk && suf_ex < kk){
    unsigned run = suf_ex;
    for (int i=63;i>=0;i--){
      unsigned c = hist[t*64+i];
      if (run + c >= kk){
        if (!which){ meta[0] = (unsigned)(t*64+i); meta[1] = run; }
        else { meta[2] = (meta[0]<<16) | (unsigned)(t*64+i); meta[3] = kk - run; }
        break;
      }
      run += c;
    }
  }
}
__global__ void k_mark(float* ws){
  unsigned* meta = (unsigned*)ws + W_META;
  unsigned* sal  = (unsigned*)ws + W_SALIDX;
  unsigned* eq   = (unsigned*)ws + W_EQIDX;
  int i = blockIdx.x*256 + threadIdx.x;
  unsigned u = __float_as_uint(ws[W_SCORE + i]);
  unsigned U = meta[2];
  if (u > U){ unsigned p = atomicAdd(&meta[5], 1u); sal[p] = (unsigned)i; }
  else if (u == U){ unsigned p = atomicAdd(&meta[4], 1u); if (p < 4096u) eq[p] = (unsigned)i; }
}
__global__ __launch_bounds__(256) void k_eqsel(float* ws){
  unsigned* meta = (unsigned*)ws + W_META;
  unsigned* sal  = (unsigned*)ws + W_SALIDX;
  unsigned* eq   = (unsigned*)ws + W_EQIDX;
  unsigned n = meta[4]; if (n > 4096u) n = 4096u;
  unsigned r = meta[3];
  for (unsigned e = threadIdx.x; e < n; e += 256){
    unsigned me = eq[e];
    unsigned rank = 0;
    for (unsigned j=0;j<n;j++) rank += (eq[j] < me) ? 1u : 0u;
    if (rank < r){ unsigned p = atomicAdd(&meta[5], 1u); sal[p] = me; }
  }
}

// ---- LayerNorm rows of 1024 (+ optional zero of a scratch range) ----
__global__ __launch_bounds__(256) void k_ln(const float* __restrict__ in,
    const float* __restrict__ g, const float* __restrict__ bt, float* __restrict__ out,
    int n_rows, float* zptr, int zlen){
  int b = blockIdx.x, tid = threadIdx.x, wv = tid>>6;
  if (b >= n_rows){
    int zb = b - n_rows;
    int i0 = zb*1024 + tid;
#pragma unroll
    for (int k=0;k<4;k++){ int i = i0 + k*256; if (i < zlen) zptr[i] = 0.f; }
    return;
  }
  const float* x = in + (size_t)b*1024;
  float4 v = *(const float4*)(x + tid*4);
  float s  = v.x+v.y+v.z+v.w;
  float s2 = v.x*v.x+v.y*v.y+v.z*v.z+v.w*v.w;
  s = wred(s); s2 = wred(s2);
  __shared__ float rs[4], rq[4];
  if ((tid&63)==0){ rs[wv]=s; rq[wv]=s2; }
  __syncthreads();
  s = rs[0]+rs[1]+rs[2]+rs[3]; s2 = rq[0]+rq[1]+rq[2]+rq[3];
  float m = s * (1.0f/1024.0f);
  float var = s2 * (1.0f/1024.0f) - m*m;
  float rstd = rsqrtf(var + 1e-5f);
  float4 gv = *(const float4*)(g + tid*4);
  float4 bv = *(const float4*)(bt + tid*4);
  float4 o;
  o.x = (v.x-m)*rstd*gv.x + bv.x; o.y = (v.y-m)*rstd*gv.y + bv.y;
  o.z = (v.z-m)*rstd*gv.z + bv.z; o.w = (v.w-m)*rstd*gv.w + bv.w;
  *(float4*)(out + (size_t)b*1024 + tid*4) = o;
}

// ---- K-chunked GEMV, f32 atomic partials; bias in chunk 0; optional GELU on input preload ----
__global__ __launch_bounds__(256) void k_gemv(const float* __restrict__ in, int in_stride,
    const float* __restrict__ W, int ldw, const float* __restrict__ bias,
    float* __restrict__ out, int out_stride, int K, int n_out, int kchunk, int gelu_in){
  extern __shared__ float sin_[];
  int tid = threadIdx.x;
  const float* inr = in + (size_t)blockIdx.y * in_stride;
  for (int i = tid*4; i < K; i += 1024){
    float4 v = *(const float4*)(inr + i);
    if (gelu_in){ v.x=gelu_f(v.x); v.y=gelu_f(v.y); v.z=gelu_f(v.z); v.w=gelu_f(v.w); }
    *(float4*)(sin_ + i) = v;
  }
  __syncthreads();
  int wid = blockIdx.x*4 + (tid>>6);
  int l = tid & 63;
  int n_os = n_out >> 8;
  int os  = (wid % n_os) * 256;
  int kch = wid / n_os;
  int f0 = kch * kchunk;
  int o = os + l*4;
  float a0=0,a1=0,a2=0,a3=0;
  if (kch==0 && bias){ a0=bias[o]; a1=bias[o+1]; a2=bias[o+2]; a3=bias[o+3]; }
  const float* Wp = W + (size_t)f0*ldw + o;
#pragma unroll 8
  for (int f=0; f<kchunk; f++){
    float sv = sin_[f0+f];
    float4 w4 = *(const float4*)(Wp + (size_t)f*ldw);
    a0 += sv*w4.x; a1 += sv*w4.y; a2 += sv*w4.z; a3 += sv*w4.w;
  }
  float* op = out + (size_t)blockIdx.y*out_stride + o;
  atomicAdd(op+0,a0); atomicAdd(op+1,a1); atomicAdd(op+2,a2); atomicAdd(op+3,a3);
}

// ---- paired single-row GEMV ----
__global__ __launch_bounds__(256) void k_gemv_pair(
    const float* __restrict__ in0, const float* __restrict__ in1,
    const float* __restrict__ W0,  const float* __restrict__ W1,
    const float* __restrict__ b0,  const float* __restrict__ b1,
    float* __restrict__ out0, float* __restrict__ out1,
    int ldw, int K, int n_out, int kchunk){
  extern __shared__ float sin_[];
  int tid = threadIdx.x;
  int item = blockIdx.y;
  const float* inr = item ? in1 : in0;
  const float* W   = item ? W1  : W0;
  const float* bias= item ? b1  : b0;
  float* out       = item ? out1: out0;
  for (int i = tid*4; i < K; i += 1024)
    *(float4*)(sin_ + i) = *(const float4*)(inr + i);
  __syncthreads();
  int wid = blockIdx.x*4 + (tid>>6);
  int l = tid & 63;
  int n_os = n_out >> 8;
  int os  = (wid % n_os) * 256;
  int kch = wid / n_os;
  int f0 = kch * kchunk;
  int o = os + l*4;
  float a0=0,a1=0,a2=0,a3=0;
  if (kch==0){ a0=bias[o]; a1=bias[o+1]; a2=bias[o+2]; a3=bias[o+3]; }
  const float* Wp = W + (size_t)f0*ldw + o;
#pragma unroll 8
  for (int f=0; f<kchunk; f++){
    float sv = sin_[f0+f];
    float4 w4 = *(const float4*)(Wp + (size_t)f*ldw);
    a0 += sv*w4.x; a1 += sv*w4.y; a2 += sv*w4.z; a3 += sv*w4.w;
  }
  float* op = out + o;
  atomicAdd(op+0,a0); atomicAdd(op+1,a1); atomicAdd(op+2,a2); atomicAdd(op+3,a3);
}

// ---- 2-token self-attention core ----
__global__ __launch_bounds__(256) void k_attn_self(float* __restrict__ ws){
  const float* qkv = ws + W_QKV;
  float* o = ws + W_OSELF;
  int tid = threadIdx.x, wv = tid>>6, l = tid&63;
#pragma unroll
  for (int p=0;p<4;p++){
    int off = (wv + p*4)*64 + l;
    float qa = qkv[off],        qb = qkv[3072+off];
    float ka = qkv[1024+off],   kb = qkv[3072+1024+off];
    float va = qkv[2048+off],   vb = qkv[3072+2048+off];
    float s00 = wred(qa*ka)*0.125f, s01 = wred(qa*kb)*0.125f;
    float s10 = wred(qb*ka)*0.125f, s11 = wred(qb*kb)*0.125f;
    float m0 = fmaxf(s00,s01); float e00=__expf(s00-m0), e01=__expf(s01-m0); float r0=1.f/(e00+e01);
    float m1 = fmaxf(s10,s11); float e10=__expf(s10-m1), e11=__expf(s11-m1); float r1=1.f/(e10+e11);
    o[off]        = (e00*va + e01*vb)*r0;
    o[1024 + off] = (e10*va + e11*vb)*r1;
  }
}

// ---- qprojk[h][d] = (Wk[d, h-slice] . qp[h-slice]) / 8 ----
__global__ __launch_bounds__(256) void k_qproj(const float* __restrict__ cgw,
    const float* __restrict__ csw, float* __restrict__ ws){
  int br = blockIdx.x >> 4, h = blockIdx.x & 15, tid = threadIdx.x;
  const float* W  = br ? csw : cgw;
  const float* qp = ws + (br ? W_QP_S : W_QP_G);
  float* qpr      = ws + (br ? W_QPROJ_S : W_QPROJ_G);
  __shared__ float qs[64];
  if (tid < 64) qs[tid] = qp[h*64 + tid];
  __syncthreads();
#pragma unroll
  for (int dd=0; dd<4; dd++){
    int d = tid*4 + dd;
    const float* wr = W + (size_t)d*3072 + 1024 + h*64;
    float acc = 0.f;
#pragma unroll
    for (int c4=0;c4<16;c4++){
      float4 w4 = *(const float4*)(wr + c4*4);
      acc += w4.x*qs[c4*4] + w4.y*qs[c4*4+1] + w4.z*qs[c4*4+2] + w4.w*qs[c4*4+3];
    }
    qpr[h*1024 + d] = acc * 0.125f;
  }
}

// ---- FUSED cross-attention pass: 512 threads = 8 waves x 2 heads.
//      Per 64-row chunk: s_h = row.qproj_h ; w=exp(s) ; acc_h += w*row ; es_h += w.
//      bf16 partials + per-chunk es; division deferred. ----
__global__ __launch_bounds__(512) void k_fused(const float* __restrict__ fr, float* __restrict__ ws){
  int b = blockIdx.x, tid = threadIdx.x, wv = tid>>6, l = tid&63;
  int br = (b >= 512) ? 1 : 0;
  int chunk = br ? b - 512 : b;
  __shared__ unsigned idx[64];
  if (br && tid < 64) idx[tid] = ((unsigned*)ws)[W_SALIDX + chunk*64 + tid];
  __syncthreads();
  const float* qpr = ws + (br ? W_QPROJ_S : W_QPROJ_G);
  int hb = wv*2;
  float4 qv[2][4];
#pragma unroll
  for (int h=0;h<2;h++)
#pragma unroll
    for (int p=0;p<4;p++)
      qv[h][p] = *(const float4*)(qpr + (size_t)(hb+h)*1024 + p*256 + l*4);
  float4 acc[2][4];
#pragma unroll
  for (int h=0;h<2;h++)
#pragma unroll
    for (int p=0;p<4;p++) acc[h][p] = make_float4(0.f,0.f,0.f,0.f);
  float es0=0.f, es1=0.f;

  int j0 = br ? (int)idx[0] : chunk*64;
  const float* rp = fr + (size_t)j0*DIM + l*4;
  float4 c0 = *(const float4*)(rp);
  float4 c1 = *(const float4*)(rp + 256);
  float4 c2 = *(const float4*)(rp + 512);
  float4 c3 = *(const float4*)(rp + 768);

  for (int r=0; r<64; r++){
    float4 n0,n1,n2,n3;
    if (r < 63){
      int jn = br ? (int)idx[r+1] : chunk*64 + r + 1;
      const float* rn = fr + (size_t)jn*DIM + l*4;
      n0 = *(const float4*)(rn);       n1 = *(const float4*)(rn + 256);
      n2 = *(const float4*)(rn + 512); n3 = *(const float4*)(rn + 768);
    }
    float s0, s1;
    s0 = c0.x*qv[0][0].x + c0.y*qv[0][0].y + c0.z*qv[0][0].z + c0.w*qv[0][0].w
       + c1.x*qv[0][1].x + c1.y*qv[0][1].y + c1.z*qv[0][1].z + c1.w*qv[0][1].w
       + c2.x*qv[0][2].x + c2.y*qv[0][2].y + c2.z*qv[0][2].z + c2.w*qv[0][2].w
       + c3.x*qv[0][3].x + c3.y*qv[0][3].y + c3.z*qv[0][3].z + c3.w*qv[0][3].w;
    s1 = c0.x*qv[1][0].x + c0.y*qv[1][0].y + c0.z*qv[1][0].z + c0.w*qv[1][0].w
       + c1.x*qv[1][1].x + c1.y*qv[1][1].y + c1.z*qv[1][1].z + c1.w*qv[1][1].w
       + c2.x*qv[1][2].x + c2.y*qv[1][2].y + c2.z*qv[1][2].z + c2.w*qv[1][2].w
       + c3.x*qv[1][3].x + c3.y*qv[1][3].y + c3.z*qv[1][3].z + c3.w*qv[1][3].w;
    s0 = wred(s0); s1 = wred(s1);
    float w0 = __expf(s0), w1 = __expf(s1);
    es0 += w0; es1 += w1;
#pragma unroll
    for (int p=0;p<4;p++){
      float4 cp = (p==0)?c0:(p==1)?c1:(p==2)?c2:c3;
      acc[0][p].x += w0*cp.x; acc[0][p].y += w0*cp.y; acc[0][p].z += w0*cp.z; acc[0][p].w += w0*cp.w;
      acc[1][p].x += w1*cp.x; acc[1][p].y += w1*cp.y; acc[1][p].z += w1*cp.z; acc[1][p].w += w1*cp.w;
    }
    if (r < 63){ c0=n0; c1=n1; c2=n2; c3=n3; }
  }
  unsigned short* pb = (unsigned short*)(ws + (br ? W_PART_S : W_PART_G));
#pragma unroll
  for (int h=0;h<2;h++)
#pragma unroll
    for (int p=0;p<4;p++){
      ushort4 u;
      u.x = bf16r(acc[h][p].x); u.y = bf16r(acc[h][p].y);
      u.z = bf16r(acc[h][p].z); u.w = bf16r(acc[h][p].w);
      *(ushort4*)(pb + (size_t)chunk*16384 + (size_t)(hb+h)*1024 + p*256 + l*4) = u;
    }
  if (l == 0){
    float* esp = ws + (br ? W_ESP_S : W_ESP_G) + (size_t)chunk*16 + hb;
    esp[0]=es0; esp[1]=es1;
  }
}

// ---- parallel chunk reduction: grid (64 flat-blocks x 20 groups).
//      y<16: global, 32 chunks each; y>=16: salient, 32 chunks each (128 total).
//      atomicAdd f32 into unnormalized ctx; es summed by the x==0 column. ----
__global__ __launch_bounds__(256) void k_psum(float* __restrict__ ws){
  int y = blockIdx.y;
  int br = (y >= 16) ? 1 : 0;
  int grp = br ? y - 16 : y;
  int tid = threadIdx.x;
  int flat = blockIdx.x*256 + tid;
  const unsigned short* pb = (const unsigned short*)(ws + (br ? W_PART_S : W_PART_G));
  size_t base = (size_t)grp*32*16384 + flat;
  float s0=0.f,s1=0.f,s2=0.f,s3=0.f;
#pragma unroll
  for (int c=0;c<8;c++){
    s0 += bf16f(pb[base + (size_t)(c*4+0)*16384]);
    s1 += bf16f(pb[base + (size_t)(c*4+1)*16384]);
    s2 += bf16f(pb[base + (size_t)(c*4+2)*16384]);
    s3 += bf16f(pb[base + (size_t)(c*4+3)*16384]);
  }
  atomicAdd(ws + (br ? W_CTX_S : W_CTX_G) + flat, (s0+s1)+(s2+s3));
  if (blockIdx.x == 0 && tid < 16){
    const float* esp = ws + (br ? W_ESP_S : W_ESP_G);
    float s = 0.f;
#pragma unroll 4
    for (int c = grp*32; c < grp*32 + 32; c++) s += esp[(size_t)c*16 + tid];
    atomicAdd(ws + (br ? W_ES_S : W_ES_G) + tid, s);
  }
}

// ---- o[h*64+l] = (ctx[h]/es[h]) . Wv[:, 2048+h*64+l] + bv ; 4 waves split K ----
__global__ __launch_bounds__(256) void k_ohead(const float* __restrict__ cgw,
    const float* __restrict__ csw, const float* __restrict__ cgb,
    const float* __restrict__ csb, float* __restrict__ ws){
  int b = blockIdx.x, tid = threadIdx.x, w = tid>>6, l = tid&63;
  int br = b >> 6; int rem = b & 63; int h = rem >> 2; int dch = rem & 3;
  const float* W  = br ? csw : cgw;
  const float* bi = br ? csb : cgb;
  const float* ctx = ws + (br ? W_CTX_S : W_CTX_G);
  const float* es  = ws + (br ? W_ES_S : W_ES_G);
  float* o = ws + (br ? W_O_S : W_O_G);
  __shared__ float cx[256];
  float invden = 1.0f / es[h];
  cx[tid] = ctx[(size_t)h*1024 + dch*256 + tid] * invden;
  __syncthreads();
  float acc = (dch==0 && w==0) ? bi[2048 + h*64 + l] : 0.f;
  const float* wp = W + (size_t)(dch*256 + w*64)*3072 + 2048 + h*64 + l;
#pragma unroll 8
  for (int i=0;i<64;i++) acc += cx[w*64 + i] * wp[(size_t)i*3072];
  atomicAdd(&o[h*64 + l], acc);
}

extern "C" void kernel_launch(void* const* d_in, const int* in_sizes, int n_in,
                              void* d_out, int out_size, void* d_ws, size_t ws_size,
                              hipStream_t stream){
  (void)in_sizes; (void)n_in; (void)out_size; (void)ws_size; (void)NT;
  const float* fr    = (const float*)d_in[0];
  const float* qb    = (const float*)d_in[1];
  const float* re    = (const float*)d_in[2];
  const float* te    = (const float*)d_in[3];
  const float* ln1g  = (const float*)d_in[4];
  const float* ln1b  = (const float*)d_in[5];
  const float* ln2g  = (const float*)d_in[6];
  const float* ln2b  = (const float*)d_in[7];
  const float* ln3g  = (const float*)d_in[8];
  const float* ln3b  = (const float*)d_in[9];
  const float* sawin = (const float*)d_in[10];
  const float* sabin = (const float*)d_in[11];
  const float* sawout= (const float*)d_in[12];
  const float* sabout= (const float*)d_in[13];
  const float* cgwin = (const float*)d_in[14];
  const float* cgbin = (const float*)d_in[15];
  const float* cgwout= (const float*)d_in[16];
  const float* cgbout= (const float*)d_in[17];
  const float* cswin = (const float*)d_in[18];
  const float* csbin = (const float*)d_in[19];
  const float* cswout= (const float*)d_in[20];
  const float* csbout= (const float*)d_in[21];
  const float* fw1   = (const float*)d_in[22];
  const float* fb1   = (const float*)d_in[23];
  const float* fw2   = (const float*)d_in[24];
  const float* fb2   = (const float*)d_in[25];
  const float* outg  = (const float*)d_in[26];
  const float* outb  = (const float*)d_in[27];
  float* ws = (float*)d_ws;

  hipLaunchKernelGGL(k_stats,  dim3(512), dim3(256), 0, stream, fr, ws);
  hipLaunchKernelGGL(k_reduce, dim3(4),   dim3(256), 0, stream, ws, qb, re, te);
  hipLaunchKernelGGL(k_hist1,  dim3(128), dim3(256), 0, stream, ws);
  hipLaunchKernelGGL(k_find,   dim3(1),   dim3(1024),0, stream, ws, 0);
  hipLaunchKernelGGL(k_hist2,  dim3(128), dim3(256), 0, stream, ws);
  hipLaunchKernelGGL(k_find,   dim3(1),   dim3(1024),0, stream, ws, 1);
  hipLaunchKernelGGL(k_mark,   dim3(128), dim3(256), 0, stream, ws);
  hipLaunchKernelGGL(k_eqsel,  dim3(1),   dim3(256), 0, stream, ws);

  for (int li=0; li<NL; li++){
    const float* l_ln1g = ln1g + (size_t)li*DIM,  *l_ln1b = ln1b + (size_t)li*DIM;
    const float* l_ln2g = ln2g + (size_t)li*DIM,  *l_ln2b = ln2b + (size_t)li*DIM;
    const float* l_ln3g = ln3g + (size_t)li*DIM,  *l_ln3b = ln3b + (size_t)li*DIM;
    const float* l_sawin = sawin + (size_t)li*DIM*3072, *l_sabin = sabin + (size_t)li*3072;
    const float* l_sawout= sawout+ (size_t)li*DIM*DIM,  *l_sabout= sabout+ (size_t)li*DIM;
    const float* l_cgwin = cgwin + (size_t)li*DIM*3072, *l_cgbin = cgbin + (size_t)li*3072;
    const float* l_cgwout= cgwout+ (size_t)li*DIM*DIM,  *l_cgbout= cgbout+ (size_t)li*DIM;
    const float* l_cswin = cswin + (size_t)li*DIM*3072, *l_csbin = csbin + (size_t)li*3072;
    const float* l_cswout= cswout+ (size_t)li*DIM*DIM,  *l_csbout= csbout+ (size_t)li*DIM;
    const float* l_fw1 = fw1 + (size_t)li*DIM*4096, *l_fb1 = fb1 + (size_t)li*4096;
    const float* l_fw2 = fw2 + (size_t)li*4096*DIM, *l_fb2 = fb2 + (size_t)li*DIM;

    // self-attention
    hipLaunchKernelGGL(k_ln, dim3(8),  dim3(256), 0, stream, ws+W_Q, l_ln1g, l_ln1b, ws+W_QLN1, 2, ws+W_QKV, 6144);
    hipLaunchKernelGGL(k_gemv, dim3(96,2), dim3(256), 1024*4, stream, ws+W_QLN1, 1024, l_sawin, 3072, l_sabin, ws+W_QKV, 3072, 1024, 3072, 32, 0);
    hipLaunchKernelGGL(k_attn_self, dim3(1), dim3(256), 0, stream, ws);
    hipLaunchKernelGGL(k_gemv, dim3(64,2), dim3(256), 1024*4, stream, ws+W_OSELF, 1024, l_sawout, 1024, l_sabout, ws+W_Q, 1024, 1024, 1024, 16, 0);

    // cross-attention: LN2 zeroes [QP_G|QP_S|O_G|O_S|ES_G|ES_S|CTX_G|CTX_S] = 36992 floats
    hipLaunchKernelGGL(k_ln, dim3(39), dim3(256), 0, stream, ws+W_Q, l_ln2g, l_ln2b, ws+W_QLN2, 2, ws+W_QP_G, 36992);
    hipLaunchKernelGGL(k_gemv_pair, dim3(64,2), dim3(256), 1024*4, stream,
                       ws+W_QLN2, ws+W_QLN2+1024, l_cgwin, l_cswin, l_cgbin, l_csbin,
                       ws+W_QP_G, ws+W_QP_S, 3072, 1024, 1024, 16);
    hipLaunchKernelGGL(k_qproj, dim3(32), dim3(256), 0, stream, l_cgwin, l_cswin, ws);
    hipLaunchKernelGGL(k_fused, dim3(640), dim3(512), 0, stream, fr, ws);
    hipLaunchKernelGGL(k_psum,  dim3(64,20), dim3(256), 0, stream, ws);
    hipLaunchKernelGGL(k_ohead, dim3(128), dim3(256), 0, stream, l_cgwin, l_cswin, l_cgbin, l_csbin, ws);
    hipLaunchKernelGGL(k_gemv_pair, dim3(64,2), dim3(256), 1024*4, stream,
                       ws+W_O_G, ws+W_O_S, l_cgwout, l_cswout, l_cgbout, l_csbout,
                       ws+W_Q, ws+W_Q+1024, 1024, 1024, 1024, 16);

    // FFN
    hipLaunchKernelGGL(k_ln, dim3(10), dim3(256), 0, stream, ws+W_Q, l_ln3g, l_ln3b, ws+W_QLN3, 2, ws+W_FFNH, 8192);
    hipLaunchKernelGGL(k_gemv, dim3(128,2), dim3(256), 1024*4, stream, ws+W_QLN3, 1024, l_fw1, 4096, l_fb1, ws+W_FFNH, 4096, 1024, 4096, 32, 0);
    hipLaunchKernelGGL(k_gemv, dim3(128,2), dim3(256), 4096*4, stream, ws+W_FFNH, 4096, l_fw2, 1024, l_fb2, ws+W_Q, 1024, 4096, 1024, 32, 1);
  }
  hipLaunchKernelGGL(k_ln, dim3(2), dim3(256), 0, stream, ws+W_Q, outg, outb, (float*)d_out, 2, nullptr, 0);
}